// Round 9
// baseline (85.245 us; speedup 1.0000x reference)
//
#include <hip/hip_runtime.h>
#include <math.h>

namespace {

constexpr int Hh = 384;
constexpr int Ww = 384;
constexpr int Bb = 4;
constexpr int HW = Hh * Ww;          // 147456
constexpr int NPIX = Bb * HW;        // 589824
constexpr int ROUNDS = 10;           // 2 mean-field iterations per round
constexpr int TPB = 256;

// 2D tiling: each block owns a 64x8 tile (2 px/thread), 6x48 tiles/batch
constexpr int TILE_W = 64;
constexpr int TILE_H = 8;
constexpr int TX = Ww / TILE_W;              // 6
constexpr int TY = Hh / TILE_H;              // 48
constexpr int BLKS_PER_B = TX * TY;          // 288
constexpr int NBLK = Bb * BLKS_PER_B;        // 1152

// width-2 halo staged per round: rows row0-2..row0+9 (12), col bytes col0-8..col0+71 (80)
constexpr int H2ROWS = 12;
constexpr int H2DW = 20;                     // 80 B / 4
constexpr int H2TOT = H2ROWS * H2DW;         // 240 dwords

// intermediate s_{2r+1}: extended region rows row0-1..row0+8 (10) x cols col0-1..col0+64 (66)
constexpr int MIDS = 68;                     // byte stride (10*68 = 680 B)
constexpr int NRING = 148;                   // 2*66 + 2*8 ring pixels

__device__ __forceinline__ float fsub_rn_(float a, float b) {
    return __fadd_rn(a, -b);
}

__device__ __forceinline__ unsigned ld_agent_u32(const void* p) {
    return __hip_atomic_load((const unsigned*)p, __ATOMIC_RELAXED,
                             __HIP_MEMORY_SCOPE_AGENT);
}
__device__ __forceinline__ void st_agent_u16(void* p, unsigned short v) {
    __hip_atomic_store((unsigned short*)p, v, __ATOMIC_RELAXED,
                       __HIP_MEMORY_SCOPE_AGENT);
}
__device__ __forceinline__ int ld_agent_i32(const int* p) {
    return __hip_atomic_load(p, __ATOMIC_RELAXED, __HIP_MEMORY_SCOPE_AGENT);
}
__device__ __forceinline__ void st_agent_i32(int* p, int v) {
    __hip_atomic_store(p, v, __ATOMIC_RELAXED, __HIP_MEMORY_SCOPE_AGENT);
}

// 9 pairwise weights for pixel (h,w) of batch-slice fmb = feature_map[b] ([3,HW])
__device__ __forceinline__ void compute_weights(const float* __restrict__ fmb,
                                                int h, int w, int hw,
                                                float* __restrict__ wgt) {
    float c0 = __fadd_rn(fmb[0 * HW + hw], 10.0f);
    float c1 = __fadd_rn(fmb[1 * HW + hw], 10.0f);
    float c2 = __fadd_rn(fmb[2 * HW + hw], 10.0f);
#pragma unroll
    for (int ki = 0; ki < 3; ++ki) {
#pragma unroll
        for (int kj = 0; kj < 3; ++kj) {
            const int k = ki * 3 + kj;
            const int hh = h + ki - 1;
            const int ww2 = w + kj - 1;
            if (hh < 0 || hh >= Hh || ww2 < 0 || ww2 >= Ww) {
                wgt[k] = 0.0f;   // OOB taps contribute exact +0.0
            } else {
                const int nhw = hh * Ww + ww2;
                float d0 = fsub_rn_(__fadd_rn(fmb[0 * HW + nhw], 10.0f), c0);
                float d1 = fsub_rn_(__fadd_rn(fmb[1 * HW + nhw], 10.0f), c1);
                float d2 = fsub_rn_(__fadd_rn(fmb[2 * HW + nhw], 10.0f), c2);
                float ss = __fadd_rn(__fadd_rn(__fmul_rn(d0, d0), __fmul_rn(d1, d1)),
                                     __fmul_rn(d2, d2));
                float color = __fdiv_rn(-ss, 0.5f);                 // /(2*0.5^2)
                const float spk = __fdiv_rn(
                    (float)((ki - 1) * (ki - 1) + (kj - 1) * (kj - 1)), 1800.0f);
                wgt[k] = __fmul_rn(3.0f, expf(fsub_rn_(color, spk)));
            }
        }
    }
}

// one mean-field pixel update; base points at the top-left (ki=0,kj=0) tap.
// Returns bit0 = (ch0 > 0.5), bit1 = (ch1 > 0.5). FP order identical to ref.
template <int STRIDE>
__device__ __forceinline__ unsigned mf_state(const unsigned char* base,
                                             const float* w9, float tpx,
                                             float Lg45, float Lg55) {
    float a0 = 0.0f, a1 = 0.0f;
#pragma unroll
    for (int ki = 0; ki < 3; ++ki) {
#pragma unroll
        for (int kj = 0; kj < 3; ++kj) {
            const int k = ki * 3 + kj;
            unsigned char s = base[ki * STRIDE + kj];   // garbage when w9[k]==0 -> +0.0
            float u0 = (s & 1) ? Lg55 : Lg45;
            float u1 = (s & 2) ? Lg55 : Lg45;
            a0 = __fadd_rn(a0, __fmul_rn(u0, w9[k]));
            a1 = __fadd_rn(a1, __fmul_rn(u1, w9[k]));
        }
    }
    float f0 = expf(-a0);
    float f1 = __fmul_rn(expf(-a1), tpx);
    f0 = __fadd_rn(f0, 1e-6f);
    f1 = __fadd_rn(f1, 1e-6f);
    float S = __fadd_rn(f0, f1);
    float f0n = __fdiv_rn(f0, S);
    float f1n = __fdiv_rn(f1, S);
    return (f0n > 0.5f ? 1u : 0u) | (f1n > 0.5f ? 2u : 0u);
}

__device__ __forceinline__ void ring_coords(int ri, int& er, int& ec) {
    if (ri < 66)       { er = 0;        ec = ri; }
    else if (ri < 132) { er = 9;        ec = ri - 66; }
    else if (ri < 140) { er = ri - 131; ec = 0; }     // 1..8
    else               { er = ri - 139; ec = 65; }    // 1..8
}

// state byte: bit0 = (channel0 == 0.55f), bit1 = (channel1 == 0.55f)
// Sync: per-block monotone flags (relaxed agent atomics at LLC — proven R5-R8).
// flag[bid] = m  <=>  s_{2(m-1)} visible. Round r consumes s_{2r}: wait
// neighbors' flag >= r+1 (also the anti-overwrite guarantee, R7/R8).
// Convergence skip: the staged 12x80 region is the COMPLETE input of a round.
// If it equals the previous round's staged bytes, then s_{2r+2}=s_{2r} and the
// write-target buffer already holds those bytes (ping-pong invariant), so the
// block skips compute+store and just publishes its flag. Bit-exact by induction.
__global__ __launch_bounds__(TPB, 8) void fused_kernel(
        const float* __restrict__ x, const float* __restrict__ t,
        const float* __restrict__ fm, float* __restrict__ out,
        int* __restrict__ arrive, int* __restrict__ flags,
        int* __restrict__ partial,
        unsigned char* __restrict__ st0, unsigned char* __restrict__ st1) {
    const int tid = threadIdx.x;
    const int bid = blockIdx.x;
    const int b = bid / BLKS_PER_B;
    const int rr_ = bid - b * BLKS_PER_B;
    const int ty = rr_ / TX, tx = rr_ - ty * TX;
    const int row0 = ty * TILE_H, col0 = tx * TILE_W;
    const int tr = tid >> 5;              // 0..7
    const int tc = (tid & 31) * 2;        // 0..62
    const int row = row0 + tr, col = col0 + tc;
    const int hw = row * Ww + col;
    const int gp = b * HW + hw;           // gp % 2 == 0

    // lanes 0..7 of wave 0 poll one neighbor each
    bool nactive = false;
    const int* nflag = nullptr;
    if (tid < 8) {
        const int l2 = (tid < 4) ? tid : tid + 1;       // skip center
        const int dy = l2 / 3 - 1, dx = l2 - (l2 / 3) * 3 - 1;
        const int nty = ty + dy, ntx = tx + dx;
        if (nty >= 0 && nty < TY && ntx >= 0 && ntx < TX) {
            nactive = true;
            nflag = &flags[(b * BLKS_PER_B + nty * TX + ntx) << 4];
        }
    }

    const float Lg45 = (float)(-log((double)0.45f));
    const float Lg55 = (float)(-log((double)0.55f));

    // ---- once: own weights+targets, ring weights+targets, init state ----
    const float* fmb = fm + (size_t)b * 3 * HW;
    float wall[2][9];
#pragma unroll
    for (int j = 0; j < 2; ++j)
        compute_weights(fmb, row, col + j, hw + j, wall[j]);

    bool ringv = false;
    int rer = 0, rec = 0;
    float rw[9] = {0, 0, 0, 0, 0, 0, 0, 0, 0};
    float rt = 0.0f;
    if (tid < NRING) {
        ring_coords(tid, rer, rec);
        const int irow = row0 - 1 + rer, icol = col0 - 1 + rec;
        ringv = (irow >= 0 && irow < Hh && icol >= 0 && icol < Ww);
        if (ringv) {
            compute_weights(fmb, irow, icol, irow * Ww + icol, rw);
            rt = t[(size_t)b * HW + irow * Ww + icol];
        }
    }

    float2 xv = reinterpret_cast<const float2*>(x)[gp >> 1];
    float2 tv = reinterpret_cast<const float2*>(t)[gp >> 1];
    const float tj[2] = {tv.x, tv.y};
    {
        unsigned short pack =
            (unsigned short)(((__fmul_rn(xv.x, tv.x) > 0.5f) ? 2u : 1u) |
                             (((__fmul_rn(xv.y, tv.y) > 0.5f) ? 2u : 1u) << 8));
        st_agent_u16(st0 + gp, pack);
    }

    __shared__ unsigned lds_h2[2][H2TOT];         // double-buffered staged halo
    __shared__ unsigned char lds_mid[10 * MIDS];  // s_{2r+1}, 10x66 used
    __shared__ int sconv[4];
    __shared__ int sred[4];

    // poison prev-buffer so round 0 never skips (state bytes are <= 3)
    if (tid < H2TOT) lds_h2[1][tid] = 0xFFFFFFFFu;

    __syncthreads();                      // drain s_0 stores (vmcnt 0)
    if (tid == 0) st_agent_i32(&flags[bid << 4], 1);

    // ---- 10 rounds x 2 iterations ----
    for (int r = 0; r < ROUNDS; ++r) {
        const bool fin = (r == ROUNDS - 1);
        const int hbuf = r & 1;
        const unsigned char* cur = (r & 1) ? st1 : st0;
        unsigned char* nxt = (r & 1) ? st0 : st1;

        // wait: all neighbors have s_{2r} visible (flag >= r+1)
        if (tid < 64) {
            const int target = r + 1;
            for (;;) {
                bool ok = true;
                if (nactive) ok = (ld_agent_i32(nflag) >= target);
                if (__all(ok)) break;
                __builtin_amdgcn_s_sleep(1);
            }
        }
        __syncthreads();

        // stage width-2 halo + compare against previous round's staged bytes
        bool eq = true;
        if (tid < H2TOT) {
            const unsigned char* base2 =
                cur + (size_t)b * HW + (row0 - 2) * Ww + (col0 - 8);
            const int hr = tid / H2DW, hc = tid - hr * H2DW;
            unsigned v = ld_agent_u32(base2 + hr * Ww + hc * 4);
            eq = (v == lds_h2[hbuf ^ 1][tid]);
            lds_h2[hbuf][tid] = v;
        }
        {
            int ok = __all(eq);
            if ((tid & 63) == 0) sconv[tid >> 6] = ok;
        }
        __syncthreads();
        const bool skip =
            (r > 0) && sconv[0] && sconv[1] && sconv[2] && sconv[3];

        const unsigned char* h2b = (const unsigned char*)lds_h2[hbuf];
        unsigned n2[2] = {0, 0};
        if (!skip) {
            // ---- step 1: s_{2r+1} on extended 10x66 region into lds_mid ----
#pragma unroll
            for (int j = 0; j < 2; ++j) {
                unsigned m = mf_state<80>(h2b + (tr + 1) * 80 + tc + 7 + j,
                                          wall[j], tj[j], Lg45, Lg55);
                lds_mid[(tr + 1) * MIDS + tc + j + 1] = (unsigned char)m;
            }
            if (ringv) {
                unsigned m = mf_state<80>(h2b + rer * 80 + rec + 6,
                                          rw, rt, Lg45, Lg55);
                lds_mid[rer * MIDS + rec] = (unsigned char)m;
            }
            __syncthreads();
            // ---- step 2: s_{2r+2} for own 2 px from lds_mid ----
#pragma unroll
            for (int j = 0; j < 2; ++j)
                n2[j] = mf_state<MIDS>(lds_mid + tr * MIDS + tc + j,
                                       wall[j], tj[j], Lg45, Lg55);
        } else {
            // s_{2r+2} = s_{2r}: own-tile bytes live in the staged halo
            n2[0] = h2b[(tr + 2) * 80 + tc + 8];
            n2[1] = h2b[(tr + 2) * 80 + tc + 9];
        }

        if (fin) {
            float o0 = (n2[0] & 2) ? 1.0f : 0.0f;
            float o1 = (n2[1] & 2) ? 1.0f : 0.0f;
            reinterpret_cast<float2*>(out)[gp >> 1] = make_float2(o0, o1);
            int cnt = (o0 != 0.0f) + (o1 != 0.0f);
            const int lane = tid & 63;
            const int wv = tid >> 6;
#pragma unroll
            for (int off = 32; off; off >>= 1) cnt += __shfl_down(cnt, off, 64);
            if (lane == 0) sred[wv] = cnt;
            __syncthreads();
            if (tid == 0) {
                int tot = sred[0] + sred[1] + sred[2] + sred[3];
                st_agent_i32(&partial[bid], tot);
            }
        } else {
            if (!skip) {
                st_agent_u16(nxt + gp,
                             (unsigned short)(n2[0] | (n2[1] << 8)));
                __syncthreads();          // drain s_{2r+2} stores
            }
            // skip: target buffer already holds s_{2r+2} (= s_{2r}); no stores pending
            if (tid == 0) st_agent_i32(&flags[bid << 4], r + 2);
        }
    }

    // ---- final global sync (partials), then block 0 reduces -> valid ----
    __syncthreads();                      // drain partial store
    if (tid == 0)
        __hip_atomic_fetch_add(&arrive[(bid & 15) << 4], 1,
                               __ATOMIC_RELAXED, __HIP_MEMORY_SCOPE_AGENT);
    if (bid == 0) {
        if (tid < 64) {
            for (;;) {
                int v = 0;
                if (tid < 16) v = ld_agent_i32(&arrive[tid << 4]);
#pragma unroll
                for (int off = 1; off < 64; off <<= 1) v += __shfl_xor(v, off, 64);
                if (v >= NBLK) break;
                __builtin_amdgcn_s_sleep(1);
            }
        }
        __syncthreads();
        const int wv = tid >> 6;          // batch 0..3
        const int lane = tid & 63;
        const int base = wv * BLKS_PER_B; // 288 partials per batch = 4x64 + 32
        int s = 0;
#pragma unroll
        for (int k = 0; k < 4; ++k) s += ld_agent_i32(&partial[base + 64 * k + lane]);
        if (lane < 32) s += ld_agent_i32(&partial[base + 256 + lane]);
#pragma unroll
        for (int off = 32; off; off >>= 1) s += __shfl_down(s, off, 64);
        if (lane == 0) {
            float cf = (float)s;
            const float lo = (float)(147456.0 * 0.05);
            const float hi = (float)(147456.0 * 0.95);
            out[NPIX + wv] = (cf >= lo && cf <= hi) ? 1.0f : 0.0f;
        }
    }
}

}  // namespace

extern "C" void kernel_launch(void* const* d_in, const int* in_sizes, int n_in,
                              void* d_out, int out_size, void* d_ws, size_t ws_size,
                              hipStream_t stream) {
    const float* x  = (const float*)d_in[0];
    const float* tg = (const float*)d_in[1];
    const float* fm = (const float*)d_in[2];
    float* out = (float*)d_out;

    char* ws = (char*)d_ws;
    // layout: [arrive 16x64B = 1024][flags 1152x64B = 73728]
    //         [partial 1152x4 = 4608][pad to 79360][st0][st1]
    int* arrive  = (int*)ws;
    int* flags   = (int*)(ws + 1024);
    int* partial = (int*)(ws + 1024 + 73728);
    unsigned char* st0 = (unsigned char*)(ws + 79360);
    unsigned char* st1 = st0 + NPIX;

    // zero arrive + flags every call (graph-captured)
    (void)hipMemsetAsync(ws, 0, 1024 + 73728, stream);

    fused_kernel<<<NBLK, TPB, 0, stream>>>(x, tg, fm, out, arrive, flags,
                                           partial, st0, st1);
}

// Round 10
// 84.204 us; speedup vs baseline: 1.0124x; 1.0124x over previous
//
#include <hip/hip_runtime.h>
#include <math.h>

namespace {

constexpr int Hh = 384;
constexpr int Ww = 384;
constexpr int Bb = 4;
constexpr int HW = Hh * Ww;          // 147456
constexpr int NPIX = Bb * HW;        // 589824
constexpr int ROUNDS = 5;            // 4 mean-field iterations per round
constexpr int TPB = 256;

// 2D tiling: each block owns a 64x8 tile (2 px/thread), 6x48 tiles/batch
constexpr int TILE_W = 64;
constexpr int TILE_H = 8;
constexpr int TX = Ww / TILE_W;              // 6
constexpr int TY = Hh / TILE_H;              // 48
constexpr int BLKS_PER_B = TX * TY;          // 288
constexpr int NBLK = Bb * BLKS_PER_B;        // 1152

// width-4 halo staged per round: rows row0-4..row0+11 (16), col bytes col0-4..col0+67 (72)
constexpr int SR = 16;
constexpr int SCB = 72;                      // byte stride
constexpr int SDW = SCB / 4;                 // 18 dwords/row
constexpr int STOT = SR * SDW;               // 288 dwords

// step-1 region: local coords lr 1..14, lc 1..70 (image rows row0-4+lr)
constexpr int REG_W = 70;
constexpr int REGN = 14 * REG_W;             // 980 pixels

__device__ __forceinline__ float fsub_rn_(float a, float b) {
    return __fadd_rn(a, -b);
}

__device__ __forceinline__ unsigned ld_agent_u32(const void* p) {
    return __hip_atomic_load((const unsigned*)p, __ATOMIC_RELAXED,
                             __HIP_MEMORY_SCOPE_AGENT);
}
__device__ __forceinline__ void st_agent_u16(void* p, unsigned short v) {
    __hip_atomic_store((unsigned short*)p, v, __ATOMIC_RELAXED,
                       __HIP_MEMORY_SCOPE_AGENT);
}
__device__ __forceinline__ int ld_agent_i32(const int* p) {
    return __hip_atomic_load(p, __ATOMIC_RELAXED, __HIP_MEMORY_SCOPE_AGENT);
}
__device__ __forceinline__ void st_agent_i32(int* p, int v) {
    __hip_atomic_store(p, v, __ATOMIC_RELAXED, __HIP_MEMORY_SCOPE_AGENT);
}

// 9 pairwise weights for pixel (h,w) of batch-slice fmb = feature_map[b] ([3,HW])
__device__ __forceinline__ void compute_weights(const float* __restrict__ fmb,
                                                int h, int w, int hw,
                                                float* __restrict__ wgt) {
    float c0 = __fadd_rn(fmb[0 * HW + hw], 10.0f);
    float c1 = __fadd_rn(fmb[1 * HW + hw], 10.0f);
    float c2 = __fadd_rn(fmb[2 * HW + hw], 10.0f);
#pragma unroll
    for (int ki = 0; ki < 3; ++ki) {
#pragma unroll
        for (int kj = 0; kj < 3; ++kj) {
            const int k = ki * 3 + kj;
            const int hh = h + ki - 1;
            const int ww2 = w + kj - 1;
            if (hh < 0 || hh >= Hh || ww2 < 0 || ww2 >= Ww) {
                wgt[k] = 0.0f;   // OOB taps contribute exact +0.0
            } else {
                const int nhw = hh * Ww + ww2;
                float d0 = fsub_rn_(__fadd_rn(fmb[0 * HW + nhw], 10.0f), c0);
                float d1 = fsub_rn_(__fadd_rn(fmb[1 * HW + nhw], 10.0f), c1);
                float d2 = fsub_rn_(__fadd_rn(fmb[2 * HW + nhw], 10.0f), c2);
                float ss = __fadd_rn(__fadd_rn(__fmul_rn(d0, d0), __fmul_rn(d1, d1)),
                                     __fmul_rn(d2, d2));
                float color = __fdiv_rn(-ss, 0.5f);                 // /(2*0.5^2)
                const float spk = __fdiv_rn(
                    (float)((ki - 1) * (ki - 1) + (kj - 1) * (kj - 1)), 1800.0f);
                wgt[k] = __fmul_rn(3.0f, expf(fsub_rn_(color, spk)));
            }
        }
    }
}

// one mean-field pixel update at stride-72 source; base -> top-left tap.
__device__ __forceinline__ unsigned mf_state72(const unsigned char* base,
                                               const float* w9, float tpx,
                                               float Lg45, float Lg55) {
    float a0 = 0.0f, a1 = 0.0f;
#pragma unroll
    for (int ki = 0; ki < 3; ++ki) {
#pragma unroll
        for (int kj = 0; kj < 3; ++kj) {
            const int k = ki * 3 + kj;
            unsigned char s = base[ki * SCB + kj];   // garbage when w9[k]==0 -> +0.0
            float u0 = (s & 1) ? Lg55 : Lg45;
            float u1 = (s & 2) ? Lg55 : Lg45;
            a0 = __fadd_rn(a0, __fmul_rn(u0, w9[k]));
            a1 = __fadd_rn(a1, __fmul_rn(u1, w9[k]));
        }
    }
    float f0 = expf(-a0);
    float f1 = __fmul_rn(expf(-a1), tpx);
    f0 = __fadd_rn(f0, 1e-6f);
    f1 = __fadd_rn(f1, 1e-6f);
    float S = __fadd_rn(f0, f1);
    float f0n = __fdiv_rn(f0, S);
    float f1n = __fdiv_rn(f1, S);
    return (f0n > 0.5f ? 1u : 0u) | (f1n > 0.5f ? 2u : 0u);
}

// Sync: per-block monotone flags (relaxed agent atomics at LLC — proven R5-R9).
// flag[bid]=m <=> s_{4(m-1)} visible. Round r consumes s_{4r}: wait neighbors'
// flag >= r+1 (also anti-overwrite, R7-R9 argument). Convergence skip (R9) +
// striped per-round conv counters; conv[r]==NBLK => field globally stable =>
// remaining rounds are identity => break with flag=ROUNDS+2 (never blocks anyone).
__global__ __launch_bounds__(TPB, 5) void fused_kernel(
        const float* __restrict__ x, const float* __restrict__ t,
        const float* __restrict__ fm, float* __restrict__ out,
        int* __restrict__ arrive, int* __restrict__ flags,
        int* __restrict__ conv, int* __restrict__ partial,
        unsigned char* __restrict__ st0, unsigned char* __restrict__ st1) {
    const int tid = threadIdx.x;
    const int bid = blockIdx.x;
    const int b = bid / BLKS_PER_B;
    const int rr_ = bid - b * BLKS_PER_B;
    const int ty = rr_ / TX, tx = rr_ - ty * TX;
    const int row0 = ty * TILE_H, col0 = tx * TILE_W;
    const int tr = tid >> 5;              // 0..7
    const int tc = (tid & 31) * 2;        // 0..62
    const int gp = b * HW + (row0 + tr) * Ww + col0 + tc;   // gp % 2 == 0

    // lanes 0..7 of wave 0 poll one neighbor each
    bool nactive = false;
    const int* nflag = nullptr;
    if (tid < 8) {
        const int l2 = (tid < 4) ? tid : tid + 1;       // skip center
        const int dy = l2 / 3 - 1, dx = l2 - (l2 / 3) * 3 - 1;
        const int nty = ty + dy, ntx = tx + dx;
        if (nty >= 0 && nty < TY && ntx >= 0 && ntx < TX) {
            nactive = true;
            nflag = &flags[(b * BLKS_PER_B + nty * TX + ntx) << 4];
        }
    }

    const float Lg45 = (float)(-log((double)0.45f));
    const float Lg55 = (float)(-log((double)0.55f));

    // ---- once: weights+targets for up to 4 region pixels per thread ----
    const float* fmb = fm + (size_t)b * 3 * HW;
    float sw[4][9];
    float stg[4];
    int svm = 0;                           // slot validity bitmask
#pragma unroll
    for (int s = 0; s < 4; ++s) {
        const int idx = tid + TPB * s;
#pragma unroll
        for (int k = 0; k < 9; ++k) sw[s][k] = 0.0f;
        stg[s] = 0.0f;
        if (idx < REGN) {
            const int lr = 1 + idx / REG_W;
            const int lc = 1 + (idx - REG_W * (idx / REG_W));
            const int ir = row0 - 4 + lr, ic = col0 - 4 + lc;
            if (ir >= 0 && ir < Hh && ic >= 0 && ic < Ww) {
                svm |= 1 << s;
                compute_weights(fmb, ir, ic, ir * Ww + ic, sw[s]);
                stg[s] = t[(size_t)b * HW + ir * Ww + ic];
            }
        }
    }

    // init state for own 2 px
    {
        float2 xv = reinterpret_cast<const float2*>(x)[gp >> 1];
        float2 tv = reinterpret_cast<const float2*>(t)[gp >> 1];
        unsigned short pack =
            (unsigned short)(((__fmul_rn(xv.x, tv.x) > 0.5f) ? 2u : 1u) |
                             (((__fmul_rn(xv.y, tv.y) > 0.5f) ? 2u : 1u) << 8));
        st_agent_u16(st0 + gp, pack);
    }

    __shared__ unsigned lds_h2[2][STOT];          // double-buffered staged halo
    __shared__ unsigned char mA[SR * SCB];        // shell ping
    __shared__ unsigned char mB[SR * SCB];        // shell pong
    __shared__ int sconv[4];
    __shared__ int sred[4];
    __shared__ int sdone;

    // poison prev-halo so round 0 never skips (state bytes <= 3)
    for (int i = tid; i < STOT; i += TPB) lds_h2[1][i] = 0xFFFFFFFFu;

    __syncthreads();                      // drain s_0 stores (vmcnt 0)
    if (tid == 0) st_agent_i32(&flags[bid << 4], 1);

    // one shell step: src/dst stride SCB, membership bounds on (lr,lc)
    auto step = [&](const unsigned char* src, unsigned char* dst,
                    int rlo, int rhi, int clo, int chi) {
#pragma unroll
        for (int s = 0; s < 4; ++s) {
            const int idx = tid + TPB * s;
            if (idx < REGN && ((svm >> s) & 1)) {
                const int lr = 1 + idx / REG_W;
                const int lc = 1 + (idx - REG_W * (idx / REG_W));
                if (lr >= rlo && lr <= rhi && lc >= clo && lc <= chi) {
                    unsigned m = mf_state72(src + (lr - 1) * SCB + (lc - 1),
                                            sw[s], stg[s], Lg45, Lg55);
                    dst[lr * SCB + lc] = (unsigned char)m;
                }
            }
        }
    };

    unsigned n0 = 0, n1 = 0;

    // ---- 5 rounds x 4 iterations ----
    for (int r = 0; r < ROUNDS; ++r) {
        const bool fin = (r == ROUNDS - 1);
        const int hbuf = r & 1;
        const unsigned char* cur = (r & 1) ? st1 : st0;
        unsigned char* nxt = (r & 1) ? st0 : st1;

        // global-done check: conv[r-1]==NBLK => field stable => break
        if (r >= 2) {
            int v = 0;
            if (tid < 16) v = ld_agent_i32(&conv[((r - 1) * 16 + tid) << 4]);
            if (tid < 64) {
#pragma unroll
                for (int off = 1; off < 64; off <<= 1) v += __shfl_xor(v, off, 64);
                if (tid == 0) sdone = (v >= NBLK);
            }
            __syncthreads();
            const bool gdone = (sdone != 0);
            if (gdone) {
                if (tid == 0) st_agent_i32(&flags[bid << 4], ROUNDS + 2);
                // my round r-1 was a skip (conv includes me) -> staged bytes stable
                const unsigned char* hb =
                    (const unsigned char*)lds_h2[(r - 1) & 1];
                n0 = hb[(4 + tr) * SCB + 4 + tc];
                n1 = hb[(4 + tr) * SCB + 5 + tc];
                break;
            }
        }

        // wait: all neighbors have s_{4r} visible (flag >= r+1)
        if (tid < 64) {
            const int target = r + 1;
            for (;;) {
                bool ok = true;
                if (nactive) ok = (ld_agent_i32(nflag) >= target);
                if (__all(ok)) break;
                __builtin_amdgcn_s_sleep(1);
            }
        }
        __syncthreads();

        // stage width-4 halo + compare vs previous round's staged bytes
        bool eq = true;
        {
            const unsigned char* base2 =
                cur + (size_t)b * HW + (row0 - 4) * Ww + (col0 - 4);
            for (int i = tid; i < STOT; i += TPB) {
                const int hr = i / SDW, hc = i - hr * SDW;
                unsigned vv = ld_agent_u32(base2 + hr * Ww + hc * 4);
                eq = eq && (vv == lds_h2[hbuf ^ 1][i]);
                lds_h2[hbuf][i] = vv;
            }
        }
        {
            int ok = __all(eq);
            if ((tid & 63) == 0) sconv[tid >> 6] = ok;
        }
        __syncthreads();
        const bool skip =
            (r > 0) && sconv[0] && sconv[1] && sconv[2] && sconv[3];

        const unsigned char* h2b = (const unsigned char*)lds_h2[hbuf];
        if (skip) {
            if (tid == 0)
                __hip_atomic_fetch_add(&conv[(r * 16 + (bid & 15)) << 4], 1,
                                       __ATOMIC_RELAXED, __HIP_MEMORY_SCOPE_AGENT);
            n0 = h2b[(4 + tr) * SCB + 4 + tc];
            n1 = h2b[(4 + tr) * SCB + 5 + tc];
        } else {
            step(h2b, mA, 1, 14, 1, 70);    // s_{4r+1} on 14x70
            __syncthreads();
            step(mA, mB, 2, 13, 2, 69);     // s_{4r+2} on 12x68
            __syncthreads();
            step(mB, mA, 3, 12, 3, 68);     // s_{4r+3} on 10x66
            __syncthreads();
            step(mA, mB, 4, 11, 4, 67);     // s_{4r+4} on own 8x64
            __syncthreads();
            n0 = mB[(4 + tr) * SCB + 4 + tc];
            n1 = mB[(4 + tr) * SCB + 5 + tc];
        }

        if (!fin) {
            if (!skip) {
                st_agent_u16(nxt + gp, (unsigned short)(n0 | (n1 << 8)));
                __syncthreads();          // drain s_{4r+4} stores
            }
            if (tid == 0) st_agent_i32(&flags[bid << 4], r + 2);
        }
    }

    // ---- output + final global sync ----
    const float o0 = (n0 & 2) ? 1.0f : 0.0f;
    const float o1 = (n1 & 2) ? 1.0f : 0.0f;
    reinterpret_cast<float2*>(out)[gp >> 1] = make_float2(o0, o1);
    {
        int cnt = (o0 != 0.0f) + (o1 != 0.0f);
        const int lane = tid & 63;
        const int wv = tid >> 6;
#pragma unroll
        for (int off = 32; off; off >>= 1) cnt += __shfl_down(cnt, off, 64);
        if (lane == 0) sred[wv] = cnt;
    }
    __syncthreads();
    if (tid == 0) {
        int tot = sred[0] + sred[1] + sred[2] + sred[3];
        st_agent_i32(&partial[bid], tot);
    }
    __syncthreads();                      // drain partial store
    if (tid == 0)
        __hip_atomic_fetch_add(&arrive[(bid & 15) << 4], 1,
                               __ATOMIC_RELAXED, __HIP_MEMORY_SCOPE_AGENT);
    if (bid == 0) {
        if (tid < 64) {
            for (;;) {
                int v = 0;
                if (tid < 16) v = ld_agent_i32(&arrive[tid << 4]);
#pragma unroll
                for (int off = 1; off < 64; off <<= 1) v += __shfl_xor(v, off, 64);
                if (v >= NBLK) break;
                __builtin_amdgcn_s_sleep(1);
            }
        }
        __syncthreads();
        const int wv = tid >> 6;          // batch 0..3
        const int lane = tid & 63;
        const int base = wv * BLKS_PER_B; // 288 partials per batch = 4x64 + 32
        int s = 0;
#pragma unroll
        for (int k = 0; k < 4; ++k) s += ld_agent_i32(&partial[base + 64 * k + lane]);
        if (lane < 32) s += ld_agent_i32(&partial[base + 256 + lane]);
#pragma unroll
        for (int off = 32; off; off >>= 1) s += __shfl_down(s, off, 64);
        if (lane == 0) {
            float cf = (float)s;
            const float lo = (float)(147456.0 * 0.05);
            const float hi = (float)(147456.0 * 0.95);
            out[NPIX + wv] = (cf >= lo && cf <= hi) ? 1.0f : 0.0f;
        }
    }
}

}  // namespace

extern "C" void kernel_launch(void* const* d_in, const int* in_sizes, int n_in,
                              void* d_out, int out_size, void* d_ws, size_t ws_size,
                              hipStream_t stream) {
    const float* x  = (const float*)d_in[0];
    const float* tg = (const float*)d_in[1];
    const float* fm = (const float*)d_in[2];
    float* out = (float*)d_out;

    char* ws = (char*)d_ws;
    // layout (bytes):
    //   arrive : 0      .. 1024      (16 x 64B)
    //   flags  : 1024   .. 74752     (1152 x 64B)
    //   conv   : 74752  .. 79872     (5 rounds x 16 stripes x 64B)
    //   partial: 79872  .. 84480     (1152 x 4, static during rounds)
    //   pad    : 84480  .. 86528     (2KB, static -> halo overhang safe)
    //   st0    : 86528  .. +NPIX
    //   pad    : 2KB    (static -> st0's bottom overhang never reads st1)
    //   st1    : .. +NPIX  (tail of ws beyond is untouched/static)
    int* arrive  = (int*)ws;
    int* flags   = (int*)(ws + 1024);
    int* conv    = (int*)(ws + 74752);
    int* partial = (int*)(ws + 79872);
    unsigned char* st0 = (unsigned char*)(ws + 86528);
    unsigned char* st1 = st0 + NPIX + 2048;

    // zero arrive + flags + conv every call (graph-captured)
    (void)hipMemsetAsync(ws, 0, 79872, stream);

    fused_kernel<<<NBLK, TPB, 0, stream>>>(x, tg, fm, out, arrive, flags,
                                           conv, partial, st0, st1);
}